// Round 2
// baseline (5208.585 us; speedup 1.0000x reference)
//
#include <hip/hip_runtime.h>
#include <math.h>

// Problem constants
#define BQ   8
#define NFQ  4096
#define INQ  512
#define NBQ  2
#define NWQ  320
#define CDQ  384
#define MQ   (BQ*NFQ)              // 32768 rows
#define NTOT (NBQ*NWQ)             // 640
#define DMOD (NBQ*CDQ)             // 768
#define QOUT ((size_t)MQ*(size_t)DMOD)  // 25165824 -> perplexity slot

// GEMM tile config: block computes 64 rows x 320 cols (one codebook)
#define BM      64
#define KC      16
#define NCHUNK  (INQ/KC)           // 32
#define THREADS 256
#define TM      8                  // rows per thread
#define TN      10                 // cols per thread
#define XSS     68                 // padded x-tile row stride (floats)

// Shared memory layout (float offsets)
#define XS0 0
#define XS1 (KC*XSS)               // 1088
#define WT0 (2*KC*XSS)             // 2176
#define WT1 (WT0 + KC*NWQ)         // 7296
#define SMEM_F (WT1 + KC*NWQ)      // 12416 floats = 49664 B
// epilogue arrays alias WT0 region (parity-0; last chunk reads parity-1)
#define MARG WT0                   // [8][320] floats
#define IDXS_OFF (WT0 + 8*NWQ)     // 64 ints

__global__ __launch_bounds__(THREADS, 3) void qk1(
    const float* __restrict__ x, const float* __restrict__ W,
    const float* __restrict__ bias, const float* __restrict__ cb,
    const float* __restrict__ gum, const int* __restrict__ maskp,
    float* __restrict__ out, float* __restrict__ partial)
{
    __shared__ __align__(16) float smem[SMEM_F];
    const int tid = threadIdx.x;
    const int mb  = blockIdx.x;          // 0..511
    const int nb  = blockIdx.y;          // 0..1
    const int m0  = mb * BM;
    const int tn  = tid & 31;            // 0..31 -> cols tn*10..+9
    const int tm  = tid >> 5;            // 0..7  -> rows tm*8..+7

    // ---- staging address precompute (all indices constant after unroll) ----
    int woff[5], wl[5];
#pragma unroll
    for (int j = 0; j < 5; ++j) {
        int l4 = tid + 256*j;            // float4 index into 16x320 tile
        int kk = l4 / 80;
        int c4 = l4 - kk*80;
        woff[j] = kk*NTOT + nb*NWQ + c4*4;   // float offset into W (chunk 0)
        wl[j]   = l4*4;                      // float offset into wt buffer
    }
    const int xr = tid >> 2;             // row 0..63
    const int xq = tid & 3;              // 16B quad 0..3
    const float* xg = x + (size_t)(m0 + xr)*INQ + xq*4;
    int xw0 = (xq*4+0)*XSS + xr, xw1 = (xq*4+1)*XSS + xr;
    int xw2 = (xq*4+2)*XSS + xr, xw3 = (xq*4+3)*XSS + xr;

    float acc[TM][TN];
#pragma unroll
    for (int i = 0; i < TM; ++i)
#pragma unroll
        for (int j = 0; j < TN; ++j) acc[i][j] = 0.f;

    // prologue: stage chunk 0 into buffer 0
    {
        float4 wv0 = *(const float4*)(W + woff[0]);
        float4 wv1 = *(const float4*)(W + woff[1]);
        float4 wv2 = *(const float4*)(W + woff[2]);
        float4 wv3 = *(const float4*)(W + woff[3]);
        float4 wv4 = *(const float4*)(W + woff[4]);
        float4 xv  = *(const float4*)(xg);
        *(float4*)(smem + WT0 + wl[0]) = wv0;
        *(float4*)(smem + WT0 + wl[1]) = wv1;
        *(float4*)(smem + WT0 + wl[2]) = wv2;
        *(float4*)(smem + WT0 + wl[3]) = wv3;
        *(float4*)(smem + WT0 + wl[4]) = wv4;
        smem[XS0 + xw0] = xv.x; smem[XS0 + xw1] = xv.y;
        smem[XS0 + xw2] = xv.z; smem[XS0 + xw3] = xv.w;
    }
    __syncthreads();

    for (int c = 0; c < NCHUNK; ++c) {
        const int buf = c & 1;
        const bool more = (c+1 < NCHUNK);
        float4 wv0, wv1, wv2, wv3, wv4, xv;
        if (more) {                      // issue next-chunk global loads early
            const float* Wc = W + (size_t)(c+1)*(KC*NTOT);
            wv0 = *(const float4*)(Wc + woff[0]);
            wv1 = *(const float4*)(Wc + woff[1]);
            wv2 = *(const float4*)(Wc + woff[2]);
            wv3 = *(const float4*)(Wc + woff[3]);
            wv4 = *(const float4*)(Wc + woff[4]);
            xv  = *(const float4*)(xg + (c+1)*KC);
        }
        const float* xb = smem + (buf ? XS1 : XS0);
        const float* wb = smem + (buf ? WT1 : WT0);
#pragma unroll
        for (int kk = 0; kk < KC; ++kk) {
            const float4 av0 = *(const float4*)(xb + kk*XSS + tm*TM);
            const float4 av1 = *(const float4*)(xb + kk*XSS + tm*TM + 4);
            const float2 bv0 = *(const float2*)(wb + kk*NWQ + tn*TN);
            const float2 bv1 = *(const float2*)(wb + kk*NWQ + tn*TN + 2);
            const float2 bv2 = *(const float2*)(wb + kk*NWQ + tn*TN + 4);
            const float2 bv3 = *(const float2*)(wb + kk*NWQ + tn*TN + 6);
            const float2 bv4 = *(const float2*)(wb + kk*NWQ + tn*TN + 8);
            const float aa[TM]  = {av0.x, av0.y, av0.z, av0.w,
                                   av1.x, av1.y, av1.z, av1.w};
            const float bbv[TN] = {bv0.x, bv0.y, bv1.x, bv1.y, bv2.x,
                                   bv2.y, bv3.x, bv3.y, bv4.x, bv4.y};
#pragma unroll
            for (int i = 0; i < TM; ++i)
#pragma unroll
                for (int j = 0; j < TN; ++j)
                    acc[i][j] = fmaf(aa[i], bbv[j], acc[i][j]);
        }
        if (more) {                      // write-late into the other buffer
            float* xo = smem + (buf ? XS0 : XS1);
            float* wo = smem + (buf ? WT0 : WT1);
            *(float4*)(wo + wl[0]) = wv0;
            *(float4*)(wo + wl[1]) = wv1;
            *(float4*)(wo + wl[2]) = wv2;
            *(float4*)(wo + wl[3]) = wv3;
            *(float4*)(wo + wl[4]) = wv4;
            xo[xw0] = xv.x; xo[xw1] = xv.y; xo[xw2] = xv.z; xo[xw3] = xv.w;
        }
        __syncthreads();
    }

    // ---- epilogue ----
    {
        const float2 b0 = *(const float2*)(bias + nb*NWQ + tn*TN);
        const float2 b1 = *(const float2*)(bias + nb*NWQ + tn*TN + 2);
        const float2 b2 = *(const float2*)(bias + nb*NWQ + tn*TN + 4);
        const float2 b3 = *(const float2*)(bias + nb*NWQ + tn*TN + 6);
        const float2 b4 = *(const float2*)(bias + nb*NWQ + tn*TN + 8);
        const float bb2[TN] = {b0.x, b0.y, b1.x, b1.y, b2.x,
                               b2.y, b3.x, b3.y, b4.x, b4.y};
#pragma unroll
        for (int i = 0; i < TM; ++i)
#pragma unroll
            for (int j = 0; j < TN; ++j) acc[i][j] += bb2[j];
    }

    int* idxs = (int*)(smem + IDXS_OFF);
    float colacc[TN];
#pragma unroll
    for (int j = 0; j < TN; ++j) colacc[j] = 0.f;

#pragma unroll
    for (int i = 0; i < TM; ++i) {
        const int r  = tm*TM + i;
        const int gm = m0 + r;
        // softmax denom (logits only) across the 32 lanes of this row group
        float mx = acc[i][0];
#pragma unroll
        for (int j = 1; j < TN; ++j) mx = fmaxf(mx, acc[i][j]);
#pragma unroll
        for (int s = 16; s >= 1; s >>= 1) mx = fmaxf(mx, __shfl_xor(mx, s, 32));
        float p[TN]; float se = 0.f;
#pragma unroll
        for (int j = 0; j < TN; ++j) { p[j] = __expf(acc[i][j] - mx); se += p[j]; }
#pragma unroll
        for (int s = 16; s >= 1; s >>= 1) se += __shfl_xor(se, s, 32);
        // gumbel argmax (y = logits + gumbel, TAU=1), first-index tie-break
        const float* gp = gum + (size_t)gm*NTOT + nb*NWQ + tn*TN;
        const float2 g0 = *(const float2*)(gp);
        const float2 g1 = *(const float2*)(gp + 2);
        const float2 g2 = *(const float2*)(gp + 4);
        const float2 g3 = *(const float2*)(gp + 6);
        const float2 g4 = *(const float2*)(gp + 8);
        const float gv[TN] = {g0.x, g0.y, g1.x, g1.y, g2.x,
                              g2.y, g3.x, g3.y, g4.x, g4.y};
        float ym = -3.0e38f; int yi = 0;
#pragma unroll
        for (int j = 0; j < TN; ++j) {
            float y = acc[i][j] + gv[j];
            if (y > ym) { ym = y; yi = tn*TN + j; }
        }
#pragma unroll
        for (int s = 16; s >= 1; s >>= 1) {
            float ov = __shfl_xor(ym, s, 32);
            int   oi = __shfl_xor(yi, s, 32);
            if (ov > ym || (ov == ym && oi < yi)) { ym = ov; yi = oi; }
        }
        if (tn == 0) idxs[r] = yi;
        // masked soft-prob accumulation (valid = mask==0)
        if (maskp[gm] == 0) {
            float inv = 1.0f / se;
#pragma unroll
            for (int j = 0; j < TN; ++j) colacc[j] += p[j] * inv;
        }
    }

    // per-block marginal partials -> workspace (deterministic, no atomics)
#pragma unroll
    for (int j = 0; j < TN; ++j) smem[MARG + tm*NWQ + tn*TN + j] = colacc[j];
    __syncthreads();
    for (int ccol = tid; ccol < NWQ; ccol += THREADS) {
        float s = 0.f;
#pragma unroll
        for (int g = 0; g < 8; ++g) s += smem[MARG + g*NWQ + ccol];
        partial[(size_t)mb*NTOT + nb*NWQ + ccol] = s;
    }

    // gather codebook rows -> quantized output
    const float* cbb = cb + (size_t)nb*NWQ*CDQ;
    for (int t = tid; t < BM*(CDQ/4); t += THREADS) {
        const int r = t / (CDQ/4);
        const int q = t - r*(CDQ/4);
        const int idx = idxs[r];
        float4 v = *(const float4*)(cbb + (size_t)idx*CDQ + q*4);
        *(float4*)(out + (size_t)(m0+r)*DMOD + (size_t)nb*CDQ + q*4) = v;
    }
}

// Reduce partials -> marginal -> perplexity
__global__ void qk2(const float* __restrict__ partial,
                    const int* __restrict__ maskp,
                    float* __restrict__ out)
{
    __shared__ int   ired[10];
    __shared__ float fred[10];
    __shared__ float s_ms;
    const int tid  = threadIdx.x;        // 0..639
    const int lane = tid & 63;
    const int wid  = tid >> 6;           // 0..9

    int ms = 0;
    for (int i = tid; i < MQ; i += 640) ms += maskp[i];
#pragma unroll
    for (int s = 32; s >= 1; s >>= 1) ms += __shfl_xor(ms, s, 64);
    if (lane == 0) ired[wid] = ms;
    __syncthreads();
    if (tid == 0) {
        int t = 0;
        for (int w = 0; w < 10; ++w) t += ired[w];
        s_ms = (float)t;
    }
    __syncthreads();

    float cs0 = 0.f, cs1 = 0.f, cs2 = 0.f, cs3 = 0.f;
    for (int mbq = 0; mbq < MQ/BM; mbq += 4) {
        cs0 += partial[(size_t)(mbq+0)*NTOT + tid];
        cs1 += partial[(size_t)(mbq+1)*NTOT + tid];
        cs2 += partial[(size_t)(mbq+2)*NTOT + tid];
        cs3 += partial[(size_t)(mbq+3)*NTOT + tid];
    }
    float cs = (cs0 + cs1) + (cs2 + cs3);
    float mar = cs / s_ms;
    float tv = mar * logf(mar + 1e-7f);
#pragma unroll
    for (int s = 32; s >= 1; s >>= 1) tv += __shfl_xor(tv, s, 64);
    if (lane == 0) fred[wid] = tv;
    __syncthreads();
    if (tid == 0) {
        float h0 = fred[0]+fred[1]+fred[2]+fred[3]+fred[4];
        float h1 = fred[5]+fred[6]+fred[7]+fred[8]+fred[9];
        out[QOUT] = expf(-h0) + expf(-h1);
    }
}

extern "C" void kernel_launch(void* const* d_in, const int* in_sizes, int n_in,
                              void* d_out, int out_size, void* d_ws, size_t ws_size,
                              hipStream_t stream) {
    const float* x    = (const float*)d_in[0];
    const float* W    = (const float*)d_in[1];
    const float* bias = (const float*)d_in[2];
    const float* cb   = (const float*)d_in[3];
    const float* gum  = (const float*)d_in[4];
    const int*   mask = (const int*)d_in[5];
    float* out = (float*)d_out;
    float* partial = (float*)d_ws;       // [512][640] f32 = 1.31 MB

    dim3 grid(MQ/BM, NBQ);
    qk1<<<grid, THREADS, 0, stream>>>(x, W, bias, cb, gum, mask, out, partial);
    qk2<<<1, 640, 0, stream>>>(partial, mask, out);
}

// Round 3
// 1774.785 us; speedup vs baseline: 2.9348x; 2.9348x over previous
//
#include <hip/hip_runtime.h>
#include <math.h>

// Problem constants
#define BQ   8
#define NFQ  4096
#define INQ  512
#define NBQ  2
#define NWQ  320
#define CDQ  384
#define MQ   (BQ*NFQ)              // 32768 rows
#define NTOT (NBQ*NWQ)             // 640
#define DMOD (NBQ*CDQ)             // 768
#define QOUT ((size_t)MQ*(size_t)DMOD)  // 25165824 -> perplexity slot

// GEMM tile config: block computes 64 rows x 320 cols (one codebook)
#define BM      64
#define KC      16
#define NCHUNK  (INQ/KC)           // 32
#define THREADS 256
#define TM      8                  // rows per thread
#define TN      10                 // cols per thread
#define XSS     68                 // padded x-tile row stride (floats)

// Shared memory layout (float offsets)
#define XS0 0
#define XS1 (KC*XSS)               // 1088
#define WT0 (2*KC*XSS)             // 2176
#define WT1 (WT0 + KC*NWQ)         // 7296
#define SMEM_F (WT1 + KC*NWQ)      // 12416 floats = 49664 B
// epilogue arrays alias WT0 region (read-after-barrier only)
#define MARG WT0                   // [8][320] floats
#define IDXS_OFF (WT0 + 8*NWQ)     // 64 ints

// ---- all-scalar accumulator machinery (NO stack arrays anywhere) ----
#define DECL_ROW(P) float P##_0=0.f,P##_1=0.f,P##_2=0.f,P##_3=0.f,P##_4=0.f, \
                          P##_5=0.f,P##_6=0.f,P##_7=0.f,P##_8=0.f,P##_9=0.f

#define ROW_FMA(P, A) \
  P##_0=fmaf((A),w_0,P##_0); P##_1=fmaf((A),w_1,P##_1); \
  P##_2=fmaf((A),w_2,P##_2); P##_3=fmaf((A),w_3,P##_3); \
  P##_4=fmaf((A),w_4,P##_4); P##_5=fmaf((A),w_5,P##_5); \
  P##_6=fmaf((A),w_6,P##_6); P##_7=fmaf((A),w_7,P##_7); \
  P##_8=fmaf((A),w_8,P##_8); P##_9=fmaf((A),w_9,P##_9)

#define ROW_BIAS(P) \
  P##_0+=bb_0; P##_1+=bb_1; P##_2+=bb_2; P##_3+=bb_3; P##_4+=bb_4; \
  P##_5+=bb_5; P##_6+=bb_6; P##_7+=bb_7; P##_8+=bb_8; P##_9+=bb_9

#define ROW_EPI(P, I) do { \
  const int r_ = tm*TM + (I); \
  const int gm_ = m0 + r_; \
  float mx = fmaxf(fmaxf(fmaxf(fmaxf(P##_0,P##_1),fmaxf(P##_2,P##_3)), \
                         fmaxf(fmaxf(P##_4,P##_5),fmaxf(P##_6,P##_7))), \
                   fmaxf(P##_8,P##_9)); \
  mx = fmaxf(mx, __shfl_xor(mx,16,32)); \
  mx = fmaxf(mx, __shfl_xor(mx, 8,32)); \
  mx = fmaxf(mx, __shfl_xor(mx, 4,32)); \
  mx = fmaxf(mx, __shfl_xor(mx, 2,32)); \
  mx = fmaxf(mx, __shfl_xor(mx, 1,32)); \
  const float p_0=__expf(P##_0-mx), p_1=__expf(P##_1-mx), p_2=__expf(P##_2-mx), \
              p_3=__expf(P##_3-mx), p_4=__expf(P##_4-mx), p_5=__expf(P##_5-mx), \
              p_6=__expf(P##_6-mx), p_7=__expf(P##_7-mx), p_8=__expf(P##_8-mx), \
              p_9=__expf(P##_9-mx); \
  float se = ((p_0+p_1)+(p_2+p_3))+((p_4+p_5)+(p_6+p_7))+(p_8+p_9); \
  se += __shfl_xor(se,16,32); se += __shfl_xor(se,8,32); \
  se += __shfl_xor(se, 4,32); se += __shfl_xor(se, 2,32); \
  se += __shfl_xor(se, 1,32); \
  const float* gp = gum + (size_t)gm_*NTOT + nb*NWQ + tn*TN; \
  const float2 g0v = *(const float2*)(gp);   const float2 g1v = *(const float2*)(gp+2); \
  const float2 g2v = *(const float2*)(gp+4); const float2 g3v = *(const float2*)(gp+6); \
  const float2 g4v = *(const float2*)(gp+8); \
  float ym = P##_0 + g0v.x; int yi = 0; float yt; \
  yt = P##_1+g0v.y; if (yt>ym){ym=yt;yi=1;} \
  yt = P##_2+g1v.x; if (yt>ym){ym=yt;yi=2;} \
  yt = P##_3+g1v.y; if (yt>ym){ym=yt;yi=3;} \
  yt = P##_4+g2v.x; if (yt>ym){ym=yt;yi=4;} \
  yt = P##_5+g2v.y; if (yt>ym){ym=yt;yi=5;} \
  yt = P##_6+g3v.x; if (yt>ym){ym=yt;yi=6;} \
  yt = P##_7+g3v.y; if (yt>ym){ym=yt;yi=7;} \
  yt = P##_8+g4v.x; if (yt>ym){ym=yt;yi=8;} \
  yt = P##_9+g4v.y; if (yt>ym){ym=yt;yi=9;} \
  yi += tn*TN; \
  { float ov; int oi; \
    ov=__shfl_xor(ym,16,32); oi=__shfl_xor(yi,16,32); if (ov>ym||(ov==ym&&oi<yi)){ym=ov;yi=oi;} \
    ov=__shfl_xor(ym, 8,32); oi=__shfl_xor(yi, 8,32); if (ov>ym||(ov==ym&&oi<yi)){ym=ov;yi=oi;} \
    ov=__shfl_xor(ym, 4,32); oi=__shfl_xor(yi, 4,32); if (ov>ym||(ov==ym&&oi<yi)){ym=ov;yi=oi;} \
    ov=__shfl_xor(ym, 2,32); oi=__shfl_xor(yi, 2,32); if (ov>ym||(ov==ym&&oi<yi)){ym=ov;yi=oi;} \
    ov=__shfl_xor(ym, 1,32); oi=__shfl_xor(yi, 1,32); if (ov>ym||(ov==ym&&oi<yi)){ym=ov;yi=oi;} } \
  if (tn == 0) idxs[r_] = yi; \
  if (maskp[gm_] == 0) { const float inv = 1.0f/se; \
    ca_0=fmaf(p_0,inv,ca_0); ca_1=fmaf(p_1,inv,ca_1); ca_2=fmaf(p_2,inv,ca_2); \
    ca_3=fmaf(p_3,inv,ca_3); ca_4=fmaf(p_4,inv,ca_4); ca_5=fmaf(p_5,inv,ca_5); \
    ca_6=fmaf(p_6,inv,ca_6); ca_7=fmaf(p_7,inv,ca_7); ca_8=fmaf(p_8,inv,ca_8); \
    ca_9=fmaf(p_9,inv,ca_9); } \
} while(0)

__global__ __launch_bounds__(THREADS, 2) void qk1(
    const float* __restrict__ x, const float* __restrict__ W,
    const float* __restrict__ bias, const float* __restrict__ cb,
    const float* __restrict__ gum, const int* __restrict__ maskp,
    float* __restrict__ out, float* __restrict__ partial)
{
    __shared__ __align__(16) float smem[SMEM_F];
    const int tid = threadIdx.x;
    const int mb  = blockIdx.x;          // 0..511
    const int nb  = blockIdx.y;          // 0..1
    const int m0  = mb * BM;
    const int tn  = tid & 31;            // 0..31 -> cols tn*10..+9
    const int tm  = tid >> 5;            // 0..7  -> rows tm*8..+7

    // ---- staging address precompute (named scalars only) ----
    const int l40 = tid,        l41 = tid+256,  l42 = tid+512,
              l43 = tid+768,    l44 = tid+1024;
    const int woff0 = (l40/80)*NTOT + nb*NWQ + (l40%80)*4;
    const int woff1 = (l41/80)*NTOT + nb*NWQ + (l41%80)*4;
    const int woff2 = (l42/80)*NTOT + nb*NWQ + (l42%80)*4;
    const int woff3 = (l43/80)*NTOT + nb*NWQ + (l43%80)*4;
    const int woff4 = (l44/80)*NTOT + nb*NWQ + (l44%80)*4;
    const int wl0 = l40*4, wl1 = l41*4, wl2 = l42*4, wl3 = l43*4, wl4 = l44*4;
    const int xr = tid >> 2;             // row 0..63
    const int xq = tid & 3;              // 16B quad 0..3
    const float* xg = x + (size_t)(m0 + xr)*INQ + xq*4;
    const int xw0 = (xq*4+0)*XSS + xr, xw1 = (xq*4+1)*XSS + xr;
    const int xw2 = (xq*4+2)*XSS + xr, xw3 = (xq*4+3)*XSS + xr;

    DECL_ROW(ac0); DECL_ROW(ac1); DECL_ROW(ac2); DECL_ROW(ac3);
    DECL_ROW(ac4); DECL_ROW(ac5); DECL_ROW(ac6); DECL_ROW(ac7);

    // prologue: stage chunk 0 into buffer 0
    {
        const float4 wv0 = *(const float4*)(W + woff0);
        const float4 wv1 = *(const float4*)(W + woff1);
        const float4 wv2 = *(const float4*)(W + woff2);
        const float4 wv3 = *(const float4*)(W + woff3);
        const float4 wv4 = *(const float4*)(W + woff4);
        const float4 xv  = *(const float4*)(xg);
        *(float4*)(smem + WT0 + wl0) = wv0;
        *(float4*)(smem + WT0 + wl1) = wv1;
        *(float4*)(smem + WT0 + wl2) = wv2;
        *(float4*)(smem + WT0 + wl3) = wv3;
        *(float4*)(smem + WT0 + wl4) = wv4;
        smem[XS0 + xw0] = xv.x; smem[XS0 + xw1] = xv.y;
        smem[XS0 + xw2] = xv.z; smem[XS0 + xw3] = xv.w;
    }
    __syncthreads();

    for (int c = 0; c < NCHUNK; ++c) {
        const int buf = c & 1;
        const bool more = (c+1 < NCHUNK);
        float4 wv0, wv1, wv2, wv3, wv4, xv;
        if (more) {                      // issue next-chunk global loads early
            const float* Wc = W + (size_t)(c+1)*(KC*NTOT);
            wv0 = *(const float4*)(Wc + woff0);
            wv1 = *(const float4*)(Wc + woff1);
            wv2 = *(const float4*)(Wc + woff2);
            wv3 = *(const float4*)(Wc + woff3);
            wv4 = *(const float4*)(Wc + woff4);
            xv  = *(const float4*)(xg + (c+1)*KC);
        }
        const float* xb = smem + (buf ? XS1 : XS0);
        const float* wb = smem + (buf ? WT1 : WT0);
#pragma unroll
        for (int kk = 0; kk < KC; ++kk) {
            const float4 av0 = *(const float4*)(xb + kk*XSS + tm*TM);
            const float4 av1 = *(const float4*)(xb + kk*XSS + tm*TM + 4);
            const float2 bv0 = *(const float2*)(wb + kk*NWQ + tn*TN);
            const float2 bv1 = *(const float2*)(wb + kk*NWQ + tn*TN + 2);
            const float2 bv2 = *(const float2*)(wb + kk*NWQ + tn*TN + 4);
            const float2 bv3 = *(const float2*)(wb + kk*NWQ + tn*TN + 6);
            const float2 bv4 = *(const float2*)(wb + kk*NWQ + tn*TN + 8);
            const float w_0=bv0.x, w_1=bv0.y, w_2=bv1.x, w_3=bv1.y, w_4=bv2.x,
                        w_5=bv2.y, w_6=bv3.x, w_7=bv3.y, w_8=bv4.x, w_9=bv4.y;
            ROW_FMA(ac0, av0.x); ROW_FMA(ac1, av0.y);
            ROW_FMA(ac2, av0.z); ROW_FMA(ac3, av0.w);
            ROW_FMA(ac4, av1.x); ROW_FMA(ac5, av1.y);
            ROW_FMA(ac6, av1.z); ROW_FMA(ac7, av1.w);
        }
        if (more) {                      // write-late into the other buffer
            float* xo = smem + (buf ? XS0 : XS1);
            float* wo = smem + (buf ? WT0 : WT1);
            *(float4*)(wo + wl0) = wv0;
            *(float4*)(wo + wl1) = wv1;
            *(float4*)(wo + wl2) = wv2;
            *(float4*)(wo + wl3) = wv3;
            *(float4*)(wo + wl4) = wv4;
            xo[xw0] = xv.x; xo[xw1] = xv.y; xo[xw2] = xv.z; xo[xw3] = xv.w;
        }
        __syncthreads();
    }

    // ---- epilogue ----
    {
        const float2 b0 = *(const float2*)(bias + nb*NWQ + tn*TN);
        const float2 b1 = *(const float2*)(bias + nb*NWQ + tn*TN + 2);
        const float2 b2 = *(const float2*)(bias + nb*NWQ + tn*TN + 4);
        const float2 b3 = *(const float2*)(bias + nb*NWQ + tn*TN + 6);
        const float2 b4 = *(const float2*)(bias + nb*NWQ + tn*TN + 8);
        const float bb_0=b0.x, bb_1=b0.y, bb_2=b1.x, bb_3=b1.y, bb_4=b2.x,
                    bb_5=b2.y, bb_6=b3.x, bb_7=b3.y, bb_8=b4.x, bb_9=b4.y;
        ROW_BIAS(ac0); ROW_BIAS(ac1); ROW_BIAS(ac2); ROW_BIAS(ac3);
        ROW_BIAS(ac4); ROW_BIAS(ac5); ROW_BIAS(ac6); ROW_BIAS(ac7);
    }

    int* idxs = (int*)(smem + IDXS_OFF);
    float ca_0=0.f,ca_1=0.f,ca_2=0.f,ca_3=0.f,ca_4=0.f,
          ca_5=0.f,ca_6=0.f,ca_7=0.f,ca_8=0.f,ca_9=0.f;

    ROW_EPI(ac0, 0); ROW_EPI(ac1, 1); ROW_EPI(ac2, 2); ROW_EPI(ac3, 3);
    ROW_EPI(ac4, 4); ROW_EPI(ac5, 5); ROW_EPI(ac6, 6); ROW_EPI(ac7, 7);

    // per-block marginal partials -> workspace (deterministic, no atomics)
    {
        float* mg = smem + MARG + tm*NWQ + tn*TN;
        mg[0]=ca_0; mg[1]=ca_1; mg[2]=ca_2; mg[3]=ca_3; mg[4]=ca_4;
        mg[5]=ca_5; mg[6]=ca_6; mg[7]=ca_7; mg[8]=ca_8; mg[9]=ca_9;
    }
    __syncthreads();
    for (int ccol = tid; ccol < NWQ; ccol += THREADS) {
        float s = 0.f;
#pragma unroll
        for (int g = 0; g < 8; ++g) s += smem[MARG + g*NWQ + ccol];
        partial[(size_t)mb*NTOT + nb*NWQ + ccol] = s;
    }

    // gather codebook rows -> quantized output
    const float* cbb = cb + (size_t)nb*NWQ*CDQ;
    for (int t = tid; t < BM*(CDQ/4); t += THREADS) {
        const int r = t / (CDQ/4);
        const int q = t - r*(CDQ/4);
        const int idx = idxs[r];
        float4 v = *(const float4*)(cbb + (size_t)idx*CDQ + q*4);
        *(float4*)(out + (size_t)(m0+r)*DMOD + (size_t)nb*CDQ + q*4) = v;
    }
}

// Reduce partials -> marginal -> perplexity
__global__ void qk2(const float* __restrict__ partial,
                    const int* __restrict__ maskp,
                    float* __restrict__ out)
{
    __shared__ int   ired[10];
    __shared__ float fred[10];
    __shared__ float s_ms;
    const int tid  = threadIdx.x;        // 0..639
    const int lane = tid & 63;
    const int wid  = tid >> 6;           // 0..9

    int ms = 0;
    for (int i = tid; i < MQ; i += 640) ms += maskp[i];
#pragma unroll
    for (int s = 32; s >= 1; s >>= 1) ms += __shfl_xor(ms, s, 64);
    if (lane == 0) ired[wid] = ms;
    __syncthreads();
    if (tid == 0) {
        int t = 0;
        for (int w = 0; w < 10; ++w) t += ired[w];
        s_ms = (float)t;
    }
    __syncthreads();

    float cs0 = 0.f, cs1 = 0.f, cs2 = 0.f, cs3 = 0.f;
    for (int mbq = 0; mbq < MQ/BM; mbq += 4) {
        cs0 += partial[(size_t)(mbq+0)*NTOT + tid];
        cs1 += partial[(size_t)(mbq+1)*NTOT + tid];
        cs2 += partial[(size_t)(mbq+2)*NTOT + tid];
        cs3 += partial[(size_t)(mbq+3)*NTOT + tid];
    }
    float cs = (cs0 + cs1) + (cs2 + cs3);
    float mar = cs / s_ms;
    float tv = mar * logf(mar + 1e-7f);
#pragma unroll
    for (int s = 32; s >= 1; s >>= 1) tv += __shfl_xor(tv, s, 64);
    if (lane == 0) fred[wid] = tv;
    __syncthreads();
    if (tid == 0) {
        float h0 = fred[0]+fred[1]+fred[2]+fred[3]+fred[4];
        float h1 = fred[5]+fred[6]+fred[7]+fred[8]+fred[9];
        out[QOUT] = expf(-h0) + expf(-h1);
    }
}

extern "C" void kernel_launch(void* const* d_in, const int* in_sizes, int n_in,
                              void* d_out, int out_size, void* d_ws, size_t ws_size,
                              hipStream_t stream) {
    const float* x    = (const float*)d_in[0];
    const float* W    = (const float*)d_in[1];
    const float* bias = (const float*)d_in[2];
    const float* cb   = (const float*)d_in[3];
    const float* gum  = (const float*)d_in[4];
    const int*   mask = (const int*)d_in[5];
    float* out = (float*)d_out;
    float* partial = (float*)d_ws;       // [512][640] f32 = 1.31 MB

    dim3 grid(MQ/BM, NBQ);
    qk1<<<grid, THREADS, 0, stream>>>(x, W, bias, cb, gum, mask, out, partial);
    qk2<<<1, 640, 0, stream>>>(partial, mask, out);
}

// Round 4
// 502.972 us; speedup vs baseline: 10.3556x; 3.5286x over previous
//
#include <hip/hip_runtime.h>
#include <math.h>

// Problem constants
#define BQ   8
#define NFQ  4096
#define INQ  512
#define NBQ  2
#define NWQ  320
#define CDQ  384
#define MQ   (BQ*NFQ)              // 32768 rows
#define NTOT (NBQ*NWQ)             // 640
#define DMOD (NBQ*CDQ)             // 768
#define QOUT ((size_t)MQ*(size_t)DMOD)  // 25165824 -> perplexity slot

// GEMM tile config: block computes 64 rows x 320 cols (one codebook)
#define BM      64
#define KC      16
#define NCHUNK  (INQ/KC)           // 32
#define THREADS 256
#define TM      8                  // rows per thread
#define TN      10                 // cols per thread
#define XSS     68                 // padded x-tile row stride (floats)

// Shared memory layout (float offsets)
#define XS0 0
#define XS1 (KC*XSS)               // 1088
#define WT0 (2*KC*XSS)             // 2176
#define WT1 (WT0 + KC*NWQ)         // 7296
#define SMEM_F (WT1 + KC*NWQ)      // 12416 floats = 49664 B
// epilogue arrays alias WT0 region (read-after-barrier only)
#define MARG WT0                   // [8][320] floats
#define IDXS_OFF (WT0 + 8*NWQ)     // 64 ints

typedef const __attribute__((address_space(1))) float gasf;
typedef __attribute__((address_space(3))) float lasf;

// ---- all-scalar accumulator machinery (NO stack arrays anywhere) ----
#define DECL_ROW(P) float P##_0=0.f,P##_1=0.f,P##_2=0.f,P##_3=0.f,P##_4=0.f, \
                          P##_5=0.f,P##_6=0.f,P##_7=0.f,P##_8=0.f,P##_9=0.f

#define ROW_FMA(P, A) \
  P##_0=fmaf((A),w_0,P##_0); P##_1=fmaf((A),w_1,P##_1); \
  P##_2=fmaf((A),w_2,P##_2); P##_3=fmaf((A),w_3,P##_3); \
  P##_4=fmaf((A),w_4,P##_4); P##_5=fmaf((A),w_5,P##_5); \
  P##_6=fmaf((A),w_6,P##_6); P##_7=fmaf((A),w_7,P##_7); \
  P##_8=fmaf((A),w_8,P##_8); P##_9=fmaf((A),w_9,P##_9)

#define ROW_BIAS(P) \
  P##_0+=bb_0; P##_1+=bb_1; P##_2+=bb_2; P##_3+=bb_3; P##_4+=bb_4; \
  P##_5+=bb_5; P##_6+=bb_6; P##_7+=bb_7; P##_8+=bb_8; P##_9+=bb_9

#define ROW_EPI(P, I) do { \
  const int r_ = tm*TM + (I); \
  const int gm_ = m0 + r_; \
  float mx = fmaxf(fmaxf(fmaxf(fmaxf(P##_0,P##_1),fmaxf(P##_2,P##_3)), \
                         fmaxf(fmaxf(P##_4,P##_5),fmaxf(P##_6,P##_7))), \
                   fmaxf(P##_8,P##_9)); \
  mx = fmaxf(mx, __shfl_xor(mx,16,32)); \
  mx = fmaxf(mx, __shfl_xor(mx, 8,32)); \
  mx = fmaxf(mx, __shfl_xor(mx, 4,32)); \
  mx = fmaxf(mx, __shfl_xor(mx, 2,32)); \
  mx = fmaxf(mx, __shfl_xor(mx, 1,32)); \
  const float p_0=__expf(P##_0-mx), p_1=__expf(P##_1-mx), p_2=__expf(P##_2-mx), \
              p_3=__expf(P##_3-mx), p_4=__expf(P##_4-mx), p_5=__expf(P##_5-mx), \
              p_6=__expf(P##_6-mx), p_7=__expf(P##_7-mx), p_8=__expf(P##_8-mx), \
              p_9=__expf(P##_9-mx); \
  float se = ((p_0+p_1)+(p_2+p_3))+((p_4+p_5)+(p_6+p_7))+(p_8+p_9); \
  se += __shfl_xor(se,16,32); se += __shfl_xor(se,8,32); \
  se += __shfl_xor(se, 4,32); se += __shfl_xor(se, 2,32); \
  se += __shfl_xor(se, 1,32); \
  const float* gp = gum + (size_t)gm_*NTOT + nb*NWQ + tn*TN; \
  const float2 g0v = *(const float2*)(gp);   const float2 g1v = *(const float2*)(gp+2); \
  const float2 g2v = *(const float2*)(gp+4); const float2 g3v = *(const float2*)(gp+6); \
  const float2 g4v = *(const float2*)(gp+8); \
  float ym = P##_0 + g0v.x; int yi = 0; float yt; \
  yt = P##_1+g0v.y; if (yt>ym){ym=yt;yi=1;} \
  yt = P##_2+g1v.x; if (yt>ym){ym=yt;yi=2;} \
  yt = P##_3+g1v.y; if (yt>ym){ym=yt;yi=3;} \
  yt = P##_4+g2v.x; if (yt>ym){ym=yt;yi=4;} \
  yt = P##_5+g2v.y; if (yt>ym){ym=yt;yi=5;} \
  yt = P##_6+g3v.x; if (yt>ym){ym=yt;yi=6;} \
  yt = P##_7+g3v.y; if (yt>ym){ym=yt;yi=7;} \
  yt = P##_8+g4v.x; if (yt>ym){ym=yt;yi=8;} \
  yt = P##_9+g4v.y; if (yt>ym){ym=yt;yi=9;} \
  yi += tn*TN; \
  { float ov; int oi; \
    ov=__shfl_xor(ym,16,32); oi=__shfl_xor(yi,16,32); if (ov>ym||(ov==ym&&oi<yi)){ym=ov;yi=oi;} \
    ov=__shfl_xor(ym, 8,32); oi=__shfl_xor(yi, 8,32); if (ov>ym||(ov==ym&&oi<yi)){ym=ov;yi=oi;} \
    ov=__shfl_xor(ym, 4,32); oi=__shfl_xor(yi, 4,32); if (ov>ym||(ov==ym&&oi<yi)){ym=ov;yi=oi;} \
    ov=__shfl_xor(ym, 2,32); oi=__shfl_xor(yi, 2,32); if (ov>ym||(ov==ym&&oi<yi)){ym=ov;yi=oi;} \
    ov=__shfl_xor(ym, 1,32); oi=__shfl_xor(yi, 1,32); if (ov>ym||(ov==ym&&oi<yi)){ym=ov;yi=oi;} } \
  if (tn == 0) idxs[r_] = yi; \
  if (maskp[gm_] == 0) { const float inv = 1.0f/se; \
    ca_0=fmaf(p_0,inv,ca_0); ca_1=fmaf(p_1,inv,ca_1); ca_2=fmaf(p_2,inv,ca_2); \
    ca_3=fmaf(p_3,inv,ca_3); ca_4=fmaf(p_4,inv,ca_4); ca_5=fmaf(p_5,inv,ca_5); \
    ca_6=fmaf(p_6,inv,ca_6); ca_7=fmaf(p_7,inv,ca_7); ca_8=fmaf(p_8,inv,ca_8); \
    ca_9=fmaf(p_9,inv,ca_9); } \
} while(0)

// one W chunk (16 x 320 floats) -> LDS via async global_load_lds, width 16
#define STAGE_W(CHUNK, WTBASE) do { \
  const float* Wc_ = W + (size_t)(CHUNK)*(KC*NTOT); \
  __builtin_amdgcn_global_load_lds((gasf*)(Wc_ + woff0), (lasf*)(smem + (WTBASE) + wl0), 16, 0, 0); \
  __builtin_amdgcn_global_load_lds((gasf*)(Wc_ + woff1), (lasf*)(smem + (WTBASE) + wl1), 16, 0, 0); \
  __builtin_amdgcn_global_load_lds((gasf*)(Wc_ + woff2), (lasf*)(smem + (WTBASE) + wl2), 16, 0, 0); \
  __builtin_amdgcn_global_load_lds((gasf*)(Wc_ + woff3), (lasf*)(smem + (WTBASE) + wl3), 16, 0, 0); \
  __builtin_amdgcn_global_load_lds((gasf*)(Wc_ + woff4), (lasf*)(smem + (WTBASE) + wl4), 16, 0, 0); \
} while(0)

__global__ __launch_bounds__(THREADS, 1) void qk1(
    const float* __restrict__ x, const float* __restrict__ W,
    const float* __restrict__ bias, const float* __restrict__ cb,
    const float* __restrict__ gum, const int* __restrict__ maskp,
    float* __restrict__ out, float* __restrict__ partial)
{
    __shared__ __align__(16) float smem[SMEM_F];
    const int tid = threadIdx.x;
    const int mb  = blockIdx.x;          // 0..511
    const int nb  = blockIdx.y;          // 0..1
    const int m0  = mb * BM;
    const int tn  = tid & 31;            // 0..31 -> cols tn*10..+9
    const int tm  = tid >> 5;            // 0..7  -> rows tm*8..+7

    // ---- staging address precompute (named scalars only) ----
    const int l40 = tid,        l41 = tid+256,  l42 = tid+512,
              l43 = tid+768,    l44 = tid+1024;
    const int woff0 = (l40/80)*NTOT + nb*NWQ + (l40%80)*4;
    const int woff1 = (l41/80)*NTOT + nb*NWQ + (l41%80)*4;
    const int woff2 = (l42/80)*NTOT + nb*NWQ + (l42%80)*4;
    const int woff3 = (l43/80)*NTOT + nb*NWQ + (l43%80)*4;
    const int woff4 = (l44/80)*NTOT + nb*NWQ + (l44%80)*4;
    const int wl0 = l40*4, wl1 = l41*4, wl2 = l42*4, wl3 = l43*4, wl4 = l44*4;
    const int xr = tid >> 2;             // row 0..63
    const int xq = tid & 3;              // 16B quad 0..3
    const float* xg = x + (size_t)(m0 + xr)*INQ + xq*4;
    const int xw0 = (xq*4+0)*XSS + xr, xw1 = (xq*4+1)*XSS + xr;
    const int xw2 = (xq*4+2)*XSS + xr, xw3 = (xq*4+3)*XSS + xr;

    DECL_ROW(ac0); DECL_ROW(ac1); DECL_ROW(ac2); DECL_ROW(ac3);
    DECL_ROW(ac4); DECL_ROW(ac5); DECL_ROW(ac6); DECL_ROW(ac7);

    // prologue: stage chunk 0 into buffer 0 (W async, x via regs)
    {
        STAGE_W(0, WT0);
        const float4 xv = *(const float4*)(xg);
        smem[XS0 + xw0] = xv.x; smem[XS0 + xw1] = xv.y;
        smem[XS0 + xw2] = xv.z; smem[XS0 + xw3] = xv.w;
    }
    __syncthreads();   // drains vmcnt -> W chunk 0 resident

    for (int c = 0; c < NCHUNK; ++c) {
        const int buf = c & 1;
        const bool more = (c+1 < NCHUNK);
        float4 xv;
        if (more) {                      // async W prefetch + x reg prefetch
            STAGE_W(c+1, buf ? WT0 : WT1);
            xv = *(const float4*)(xg + (c+1)*KC);
        }
        const float* xb = smem + (buf ? XS1 : XS0);
        const float* wb = smem + (buf ? WT1 : WT0);
#pragma unroll
        for (int kk = 0; kk < KC; ++kk) {
            const float4 av0 = *(const float4*)(xb + kk*XSS + tm*TM);
            const float4 av1 = *(const float4*)(xb + kk*XSS + tm*TM + 4);
            const float2 bv0 = *(const float2*)(wb + kk*NWQ + tn*TN);
            const float2 bv1 = *(const float2*)(wb + kk*NWQ + tn*TN + 2);
            const float2 bv2 = *(const float2*)(wb + kk*NWQ + tn*TN + 4);
            const float2 bv3 = *(const float2*)(wb + kk*NWQ + tn*TN + 6);
            const float2 bv4 = *(const float2*)(wb + kk*NWQ + tn*TN + 8);
            const float w_0=bv0.x, w_1=bv0.y, w_2=bv1.x, w_3=bv1.y, w_4=bv2.x,
                        w_5=bv2.y, w_6=bv3.x, w_7=bv3.y, w_8=bv4.x, w_9=bv4.y;
            ROW_FMA(ac0, av0.x); ROW_FMA(ac1, av0.y);
            ROW_FMA(ac2, av0.z); ROW_FMA(ac3, av0.w);
            ROW_FMA(ac4, av1.x); ROW_FMA(ac5, av1.y);
            ROW_FMA(ac6, av1.z); ROW_FMA(ac7, av1.w);
        }
        if (more) {                      // write-late x into the other buffer
            float* xo = smem + (buf ? XS0 : XS1);
            xo[xw0] = xv.x; xo[xw1] = xv.y; xo[xw2] = xv.z; xo[xw3] = xv.w;
        }
        __syncthreads();                 // drains vmcnt -> next W chunk resident
    }

    // ---- epilogue ----
    {
        const float2 b0 = *(const float2*)(bias + nb*NWQ + tn*TN);
        const float2 b1 = *(const float2*)(bias + nb*NWQ + tn*TN + 2);
        const float2 b2 = *(const float2*)(bias + nb*NWQ + tn*TN + 4);
        const float2 b3 = *(const float2*)(bias + nb*NWQ + tn*TN + 6);
        const float2 b4 = *(const float2*)(bias + nb*NWQ + tn*TN + 8);
        const float bb_0=b0.x, bb_1=b0.y, bb_2=b1.x, bb_3=b1.y, bb_4=b2.x,
                    bb_5=b2.y, bb_6=b3.x, bb_7=b3.y, bb_8=b4.x, bb_9=b4.y;
        ROW_BIAS(ac0); ROW_BIAS(ac1); ROW_BIAS(ac2); ROW_BIAS(ac3);
        ROW_BIAS(ac4); ROW_BIAS(ac5); ROW_BIAS(ac6); ROW_BIAS(ac7);
    }

    int* idxs = (int*)(smem + IDXS_OFF);
    float ca_0=0.f,ca_1=0.f,ca_2=0.f,ca_3=0.f,ca_4=0.f,
          ca_5=0.f,ca_6=0.f,ca_7=0.f,ca_8=0.f,ca_9=0.f;

    ROW_EPI(ac0, 0); ROW_EPI(ac1, 1); ROW_EPI(ac2, 2); ROW_EPI(ac3, 3);
    ROW_EPI(ac4, 4); ROW_EPI(ac5, 5); ROW_EPI(ac6, 6); ROW_EPI(ac7, 7);

    // per-block marginal partials -> workspace (deterministic, no atomics)
    {
        float* mg = smem + MARG + tm*NWQ + tn*TN;
        mg[0]=ca_0; mg[1]=ca_1; mg[2]=ca_2; mg[3]=ca_3; mg[4]=ca_4;
        mg[5]=ca_5; mg[6]=ca_6; mg[7]=ca_7; mg[8]=ca_8; mg[9]=ca_9;
    }
    __syncthreads();
    for (int ccol = tid; ccol < NWQ; ccol += THREADS) {
        float s = 0.f;
#pragma unroll
        for (int g = 0; g < 8; ++g) s += smem[MARG + g*NWQ + ccol];
        partial[(size_t)mb*NTOT + nb*NWQ + ccol] = s;
    }

    // gather codebook rows -> quantized output
    const float* cbb = cb + (size_t)nb*NWQ*CDQ;
    for (int t = tid; t < BM*(CDQ/4); t += THREADS) {
        const int r = t / (CDQ/4);
        const int q = t - r*(CDQ/4);
        const int idx = idxs[r];
        float4 v = *(const float4*)(cbb + (size_t)idx*CDQ + q*4);
        *(float4*)(out + (size_t)(m0+r)*DMOD + (size_t)nb*CDQ + q*4) = v;
    }
}

// Reduce partials -> marginal -> perplexity
__global__ void qk2(const float* __restrict__ partial,
                    const int* __restrict__ maskp,
                    float* __restrict__ out)
{
    __shared__ int   ired[10];
    __shared__ float fred[10];
    __shared__ float s_ms;
    const int tid  = threadIdx.x;        // 0..639
    const int lane = tid & 63;
    const int wid  = tid >> 6;           // 0..9

    int ms = 0;
    for (int i = tid; i < MQ; i += 640) ms += maskp[i];
#pragma unroll
    for (int s = 32; s >= 1; s >>= 1) ms += __shfl_xor(ms, s, 64);
    if (lane == 0) ired[wid] = ms;
    __syncthreads();
    if (tid == 0) {
        int t = 0;
        for (int w = 0; w < 10; ++w) t += ired[w];
        s_ms = (float)t;
    }
    __syncthreads();

    float cs0 = 0.f, cs1 = 0.f, cs2 = 0.f, cs3 = 0.f;
    for (int mbq = 0; mbq < MQ/BM; mbq += 4) {
        cs0 += partial[(size_t)(mbq+0)*NTOT + tid];
        cs1 += partial[(size_t)(mbq+1)*NTOT + tid];
        cs2 += partial[(size_t)(mbq+2)*NTOT + tid];
        cs3 += partial[(size_t)(mbq+3)*NTOT + tid];
    }
    float cs = (cs0 + cs1) + (cs2 + cs3);
    float mar = cs / s_ms;
    float tv = mar * logf(mar + 1e-7f);
#pragma unroll
    for (int s = 32; s >= 1; s >>= 1) tv += __shfl_xor(tv, s, 64);
    if (lane == 0) fred[wid] = tv;
    __syncthreads();
    if (tid == 0) {
        float h0 = fred[0]+fred[1]+fred[2]+fred[3]+fred[4];
        float h1 = fred[5]+fred[6]+fred[7]+fred[8]+fred[9];
        out[QOUT] = expf(-h0) + expf(-h1);
    }
}

extern "C" void kernel_launch(void* const* d_in, const int* in_sizes, int n_in,
                              void* d_out, int out_size, void* d_ws, size_t ws_size,
                              hipStream_t stream) {
    const float* x    = (const float*)d_in[0];
    const float* W    = (const float*)d_in[1];
    const float* bias = (const float*)d_in[2];
    const float* cb   = (const float*)d_in[3];
    const float* gum  = (const float*)d_in[4];
    const int*   mask = (const int*)d_in[5];
    float* out = (float*)d_out;
    float* partial = (float*)d_ws;       // [512][640] f32 = 1.31 MB

    dim3 grid(MQ/BM, NBQ);
    qk1<<<grid, THREADS, 0, stream>>>(x, W, bias, cb, gum, mask, out, partial);
    qk2<<<1, 640, 0, stream>>>(partial, mask, out);
}

// Round 5
// 121.126 us; speedup vs baseline: 43.0014x; 4.1525x over previous
//
#include <hip/hip_runtime.h>
#include <math.h>

// Problem constants
#define BQ   8
#define NFQ  4096
#define INQ  512
#define NBQ  2
#define NWQ  320
#define CDQ  384
#define MQ   (BQ*NFQ)              // 32768 rows
#define NTOT (NBQ*NWQ)             // 640
#define DMOD (NBQ*CDQ)             // 768
#define QOUT ((size_t)MQ*(size_t)DMOD)  // perplexity slot

#define THREADS 256
#define BM 64
#define BK 32
#define NCH (INQ/BK)               // 16 chunks

// LDS byte layout: A dbuf 2x4KB, B dbuf 2x20KB
#define A0B 0
#define A1B 4096
#define B0B 8192
#define B1B 28672
#define SMEMB 49152
// epilogue overlays (inside A0 region, used after final barrier)
#define SSUMB 0      // float [4][64]
#define AYMB  1024   // float [4][64]
#define AIDXB 2048   // int   [4][64]
#define SCB   3072   // float [64]
#define IDXB  3328   // int   [64]

typedef __attribute__((ext_vector_type(4))) float f32x4;
typedef __attribute__((ext_vector_type(8))) short short8;
typedef const __attribute__((address_space(1))) unsigned short gas_us;
typedef __attribute__((address_space(3))) unsigned short las_us;

static __device__ __forceinline__ unsigned f2bf(float f) {
    unsigned u = __float_as_uint(f);
    return (u + 0x7FFFu + ((u >> 16) & 1u)) >> 16;   // RNE
}

#define DECL_ACC(M) f32x4 acc##M##0={0,0,0,0}, acc##M##1={0,0,0,0}, \
    acc##M##2={0,0,0,0}, acc##M##3={0,0,0,0}, acc##M##4={0,0,0,0}

#define MROW(M) \
  acc##M##0 = __builtin_amdgcn_mfma_f32_16x16x32_bf16(fa##M, fb0, acc##M##0,0,0,0); \
  acc##M##1 = __builtin_amdgcn_mfma_f32_16x16x32_bf16(fa##M, fb1, acc##M##1,0,0,0); \
  acc##M##2 = __builtin_amdgcn_mfma_f32_16x16x32_bf16(fa##M, fb2, acc##M##2,0,0,0); \
  acc##M##3 = __builtin_amdgcn_mfma_f32_16x16x32_bf16(fa##M, fb3, acc##M##3,0,0,0); \
  acc##M##4 = __builtin_amdgcn_mfma_f32_16x16x32_bf16(fa##M, fb4, acc##M##4,0,0,0);

#define ADDB(M) \
  acc##M##0 = acc##M##0 + b0v; acc##M##1 = acc##M##1 + b1v; \
  acc##M##2 = acc##M##2 + b2v; acc##M##3 = acc##M##3 + b3v; \
  acc##M##4 = acc##M##4 + b4v;

// B chunk (32k x 320col bf16) -> LDS via async global_load_lds, width 16.
// LDS logical layout: [col][k] bf16, 64B/col, 16B slot s = kg ^ ((col>>1)&3).
// Source pre-swizzled so linear lane*16 dest lands swizzled (rule 21).
#define STAGE_B(KC, BASE) do { \
  const unsigned short* wp_ = WtB + (KC)*BK; \
  __builtin_amdgcn_global_load_lds((gas_us*)(wp_ + gb0), (las_us*)(smem + (BASE) + lo0), 16, 0, 0); \
  __builtin_amdgcn_global_load_lds((gas_us*)(wp_ + gb1), (las_us*)(smem + (BASE) + lo1), 16, 0, 0); \
  __builtin_amdgcn_global_load_lds((gas_us*)(wp_ + gb2), (las_us*)(smem + (BASE) + lo2), 16, 0, 0); \
  __builtin_amdgcn_global_load_lds((gas_us*)(wp_ + gb3), (las_us*)(smem + (BASE) + lo3), 16, 0, 0); \
  __builtin_amdgcn_global_load_lds((gas_us*)(wp_ + gb4), (las_us*)(smem + (BASE) + lo4), 16, 0, 0); \
} while(0)

// sum+argmax per output row (M,R): row = M*16 + q*4 + R
#define EPI1(M,R) do { \
  const int row_ = M*16 + q*4 + R; \
  const int gm_  = m0 + row_; \
  float s_ = __expf(acc##M##0[R]) + __expf(acc##M##1[R]) + __expf(acc##M##2[R]) \
           + __expf(acc##M##3[R]) + __expf(acc##M##4[R]); \
  s_ += __shfl_xor(s_,1,64); s_ += __shfl_xor(s_,2,64); \
  s_ += __shfl_xor(s_,4,64); s_ += __shfl_xor(s_,8,64); \
  const float* gp_ = gum + (size_t)gm_*NTOT + nb*NWQ + w*80 + c15; \
  float ym_ = acc##M##0[R] + gp_[0]; int yi_ = c15; float yt_; \
  yt_ = acc##M##1[R] + gp_[16]; if (yt_>ym_){ym_=yt_; yi_=16+c15;} \
  yt_ = acc##M##2[R] + gp_[32]; if (yt_>ym_){ym_=yt_; yi_=32+c15;} \
  yt_ = acc##M##3[R] + gp_[48]; if (yt_>ym_){ym_=yt_; yi_=48+c15;} \
  yt_ = acc##M##4[R] + gp_[64]; if (yt_>ym_){ym_=yt_; yi_=64+c15;} \
  yi_ += w*80; \
  { float ov_; int oi_; \
    ov_=__shfl_xor(ym_,1,64); oi_=__shfl_xor(yi_,1,64); if(ov_>ym_||(ov_==ym_&&oi_<yi_)){ym_=ov_;yi_=oi_;} \
    ov_=__shfl_xor(ym_,2,64); oi_=__shfl_xor(yi_,2,64); if(ov_>ym_||(ov_==ym_&&oi_<yi_)){ym_=ov_;yi_=oi_;} \
    ov_=__shfl_xor(ym_,4,64); oi_=__shfl_xor(yi_,4,64); if(ov_>ym_||(ov_==ym_&&oi_<yi_)){ym_=ov_;yi_=oi_;} \
    ov_=__shfl_xor(ym_,8,64); oi_=__shfl_xor(yi_,8,64); if(ov_>ym_||(ov_==ym_&&oi_<yi_)){ym_=ov_;yi_=oi_;} } \
  if (c15 == 0) { \
    ((float*)(smem+SSUMB))[w*64 + row_] = s_; \
    ((float*)(smem+AYMB ))[w*64 + row_] = ym_; \
    ((int*  )(smem+AIDXB))[w*64 + row_] = yi_; } \
} while(0)

// masked marginal accumulation (sc = valid/se per row, from LDS)
#define EPI2(M,R) do { \
  const int row_ = M*16 + q*4 + R; \
  const float sc_ = ((float*)(smem+SCB))[row_]; \
  ca0 = fmaf(__expf(acc##M##0[R]), sc_, ca0); \
  ca1 = fmaf(__expf(acc##M##1[R]), sc_, ca1); \
  ca2 = fmaf(__expf(acc##M##2[R]), sc_, ca2); \
  ca3 = fmaf(__expf(acc##M##3[R]), sc_, ca3); \
  ca4 = fmaf(__expf(acc##M##4[R]), sc_, ca4); \
} while(0)

// ---- W (fp32 [512][640]) -> Wt (bf16 [640][512], transposed) ----
__global__ __launch_bounds__(256) void wcvt(const float* __restrict__ W,
                                            unsigned short* __restrict__ Wt)
{
    __shared__ __align__(16) float sm[64][68];   // odd-ish stride, 16B-aligned rows
    const int kb = blockIdx.x, cbk = blockIdx.y;
    const int tid = threadIdx.x;
    const int r = tid >> 2, qq = tid & 3;
    const float* wp = W + (size_t)(kb*64 + r)*NTOT + cbk*64;
    *(float4*)(&sm[r][(qq   )*4]) = *(const float4*)(wp + (qq   )*4);
    *(float4*)(&sm[r][(qq+ 4)*4]) = *(const float4*)(wp + (qq+ 4)*4);
    *(float4*)(&sm[r][(qq+ 8)*4]) = *(const float4*)(wp + (qq+ 8)*4);
    *(float4*)(&sm[r][(qq+12)*4]) = *(const float4*)(wp + (qq+12)*4);
    __syncthreads();
    const int cc = tid >> 2, kq = tid & 3;
    const int k0 = kq * 16;
    const float v0=sm[k0+0][cc],  v1=sm[k0+1][cc],  v2=sm[k0+2][cc],  v3=sm[k0+3][cc],
                v4=sm[k0+4][cc],  v5=sm[k0+5][cc],  v6=sm[k0+6][cc],  v7=sm[k0+7][cc],
                v8=sm[k0+8][cc],  v9=sm[k0+9][cc],  v10=sm[k0+10][cc],v11=sm[k0+11][cc],
                v12=sm[k0+12][cc],v13=sm[k0+13][cc],v14=sm[k0+14][cc],v15=sm[k0+15][cc];
    const unsigned u0 = f2bf(v0)  | (f2bf(v1) <<16), u1 = f2bf(v2)  | (f2bf(v3) <<16),
                   u2 = f2bf(v4)  | (f2bf(v5) <<16), u3 = f2bf(v6)  | (f2bf(v7) <<16),
                   u4 = f2bf(v8)  | (f2bf(v9) <<16), u5 = f2bf(v10) | (f2bf(v11)<<16),
                   u6 = f2bf(v12) | (f2bf(v13)<<16), u7 = f2bf(v14) | (f2bf(v15)<<16);
    unsigned short* op = Wt + (size_t)(cbk*64 + cc)*INQ + kb*64 + k0;
    *(uint4*)(op)     = make_uint4(u0,u1,u2,u3);
    *(uint4*)(op + 8) = make_uint4(u4,u5,u6,u7);
}

__global__ __launch_bounds__(THREADS, 2) void qk1(
    const float* __restrict__ x, const unsigned short* __restrict__ Wt,
    const float* __restrict__ bias, const float* __restrict__ cb,
    const float* __restrict__ gum, const int* __restrict__ maskp,
    float* __restrict__ out, float* __restrict__ partial)
{
    __shared__ __align__(16) char smem[SMEMB];
    const int tid = threadIdx.x;
    const int mb = blockIdx.x, nb = blockIdx.y;
    const int m0 = mb * BM;
    const int w = tid >> 6, l = tid & 63, q = l >> 4, c15 = l & 15;

    // ---- B staging constants (5 async loads/thread, pre-swizzled source) ----
    const int sB = tid & 3;
    const int colj0 = (tid      ) >> 2, colj1 = (tid +  256) >> 2,
              colj2 = (tid + 512) >> 2, colj3 = (tid +  768) >> 2,
              colj4 = (tid +1024) >> 2;
    const int kgj0 = sB ^ ((colj0 >> 1) & 3), kgj1 = sB ^ ((colj1 >> 1) & 3),
              kgj2 = sB ^ ((colj2 >> 1) & 3), kgj3 = sB ^ ((colj3 >> 1) & 3),
              kgj4 = sB ^ ((colj4 >> 1) & 3);
    const unsigned short* WtB = Wt + (size_t)nb * NWQ * INQ;
    const int gb0 = colj0*INQ + kgj0*8, gb1 = colj1*INQ + kgj1*8,
              gb2 = colj2*INQ + kgj2*8, gb3 = colj3*INQ + kgj3*8,
              gb4 = colj4*INQ + kgj4*8;
    const int lo0 = (tid      )*16, lo1 = (tid+ 256)*16, lo2 = (tid+ 512)*16,
              lo3 = (tid+ 768)*16, lo4 = (tid+1024)*16;

    // ---- x (A) staging constants: row = tid>>2, k-octet h = tid&3 ----
    const int xrow = tid >> 2, xh = tid & 3;
    const float* xg = x + (size_t)(m0 + xrow)*INQ + xh*8;
    const int axw = xrow*64 + ((xh ^ ((xrow >> 1) & 3)) * 16);

    // ---- fragment read offsets (kg = q, swizzle slot = kg ^ ((c15>>1)&3)) ----
    const int sw = (c15 >> 1) & 3;
    const int aoff = c15*64 + ((q ^ sw) * 16);
    const int boff = (w*80 + c15)*64 + ((q ^ sw) * 16);

    DECL_ACC(0); DECL_ACC(1); DECL_ACC(2); DECL_ACC(3);

    // prologue: stage chunk 0
    {
        STAGE_B(0, B0B);
        const float4 xv0 = *(const float4*)(xg);
        const float4 xv1 = *(const float4*)(xg + 4);
        const unsigned u0 = f2bf(xv0.x) | (f2bf(xv0.y)<<16),
                       u1 = f2bf(xv0.z) | (f2bf(xv0.w)<<16),
                       u2 = f2bf(xv1.x) | (f2bf(xv1.y)<<16),
                       u3 = f2bf(xv1.z) | (f2bf(xv1.w)<<16);
        *(uint4*)(smem + A0B + axw) = make_uint4(u0,u1,u2,u3);
    }
    __syncthreads();

#pragma unroll 2
    for (int kc = 0; kc < NCH; ++kc) {
        const int p = kc & 1;
        const int Acur = p ? A1B : A0B;
        const int Bcur = p ? B1B : B0B;
        const int Anx  = p ? A0B : A1B;
        const int Bnx  = p ? B0B : B1B;
        float4 xv0, xv1;
        if (kc + 1 < NCH) {              // issue next-chunk loads early (T14)
            STAGE_B(kc + 1, Bnx);
            xv0 = *(const float4*)(xg + (kc+1)*BK);
            xv1 = *(const float4*)(xg + (kc+1)*BK + 4);
        }
        const short8 fa0 = *(const short8*)(smem + Acur + aoff);
        const short8 fa1 = *(const short8*)(smem + Acur + aoff + 1024);
        const short8 fa2 = *(const short8*)(smem + Acur + aoff + 2048);
        const short8 fa3 = *(const short8*)(smem + Acur + aoff + 3072);
        const short8 fb0 = *(const short8*)(smem + Bcur + boff);
        const short8 fb1 = *(const short8*)(smem + Bcur + boff + 1024);
        const short8 fb2 = *(const short8*)(smem + Bcur + boff + 2048);
        const short8 fb3 = *(const short8*)(smem + Bcur + boff + 3072);
        const short8 fb4 = *(const short8*)(smem + Bcur + boff + 4096);
        MROW(0); MROW(1); MROW(2); MROW(3);
        if (kc + 1 < NCH) {              // write-late x->bf16->LDS
            const unsigned u0 = f2bf(xv0.x) | (f2bf(xv0.y)<<16),
                           u1 = f2bf(xv0.z) | (f2bf(xv0.w)<<16),
                           u2 = f2bf(xv1.x) | (f2bf(xv1.y)<<16),
                           u3 = f2bf(xv1.z) | (f2bf(xv1.w)<<16);
            *(uint4*)(smem + Anx + axw) = make_uint4(u0,u1,u2,u3);
        }
        __syncthreads();
    }

    // ---- epilogue ----
    const float* bp = bias + nb*NWQ + w*80 + c15;
    const float b0v = bp[0], b1v = bp[16], b2v = bp[32], b3v = bp[48], b4v = bp[64];
    ADDB(0); ADDB(1); ADDB(2); ADDB(3);

    EPI1(0,0); EPI1(0,1); EPI1(0,2); EPI1(0,3);
    EPI1(1,0); EPI1(1,1); EPI1(1,2); EPI1(1,3);
    EPI1(2,0); EPI1(2,1); EPI1(2,2); EPI1(2,3);
    EPI1(3,0); EPI1(3,1); EPI1(3,2); EPI1(3,3);
    __syncthreads();

    if (tid < BM) {
        const int row = tid;
        const float* ssum = (const float*)(smem + SSUMB);
        const float* aym  = (const float*)(smem + AYMB);
        const int*   aidx = (const int*)(smem + AIDXB);
        const float se = ssum[row] + ssum[64+row] + ssum[128+row] + ssum[192+row];
        const float vf = (maskp[m0 + row] == 0) ? 1.0f : 0.0f;
        ((float*)(smem + SCB))[row] = vf / se;
        float bv = aym[row]; int bi = aidx[row];
        float ov; int oi;
        ov = aym[ 64+row]; oi = aidx[ 64+row]; if (ov>bv || (ov==bv && oi<bi)) { bv=ov; bi=oi; }
        ov = aym[128+row]; oi = aidx[128+row]; if (ov>bv || (ov==bv && oi<bi)) { bv=ov; bi=oi; }
        ov = aym[192+row]; oi = aidx[192+row]; if (ov>bv || (ov==bv && oi<bi)) { bv=ov; bi=oi; }
        ((int*)(smem + IDXB))[row] = bi;
    }
    __syncthreads();

    float ca0=0.f, ca1=0.f, ca2=0.f, ca3=0.f, ca4=0.f;
    EPI2(0,0); EPI2(0,1); EPI2(0,2); EPI2(0,3);
    EPI2(1,0); EPI2(1,1); EPI2(1,2); EPI2(1,3);
    EPI2(2,0); EPI2(2,1); EPI2(2,2); EPI2(2,3);
    EPI2(3,0); EPI2(3,1); EPI2(3,2); EPI2(3,3);
    ca0 += __shfl_xor(ca0,16,64); ca0 += __shfl_xor(ca0,32,64);
    ca1 += __shfl_xor(ca1,16,64); ca1 += __shfl_xor(ca1,32,64);
    ca2 += __shfl_xor(ca2,16,64); ca2 += __shfl_xor(ca2,32,64);
    ca3 += __shfl_xor(ca3,16,64); ca3 += __shfl_xor(ca3,32,64);
    ca4 += __shfl_xor(ca4,16,64); ca4 += __shfl_xor(ca4,32,64);
    if (l < 16) {
        float* pp = partial + (size_t)mb*NTOT + nb*NWQ + w*80 + c15;
        pp[0]=ca0; pp[16]=ca1; pp[32]=ca2; pp[48]=ca3; pp[64]=ca4;
    }

    // gather codebook rows -> quantized output
    const float* cbb = cb + (size_t)nb*NWQ*CDQ;
    const int* idxs = (const int*)(smem + IDXB);
    for (int t = tid; t < BM*(CDQ/4); t += THREADS) {
        const int r = t / (CDQ/4);
        const int qq = t - r*(CDQ/4);
        const int idx = idxs[r];
        float4 v = *(const float4*)(cbb + (size_t)idx*CDQ + qq*4);
        *(float4*)(out + (size_t)(m0+r)*DMOD + (size_t)nb*CDQ + qq*4) = v;
    }
}

// Reduce partials -> marginal -> perplexity
__global__ void qk2(const float* __restrict__ partial,
                    const int* __restrict__ maskp,
                    float* __restrict__ out)
{
    __shared__ int   ired[10];
    __shared__ float fred[10];
    __shared__ float s_ms;
    const int tid  = threadIdx.x;        // 0..639
    const int lane = tid & 63;
    const int wid  = tid >> 6;           // 0..9

    int ms = 0;
    for (int i = tid; i < MQ; i += 640) ms += maskp[i];
#pragma unroll
    for (int s = 32; s >= 1; s >>= 1) ms += __shfl_xor(ms, s, 64);
    if (lane == 0) ired[wid] = ms;
    __syncthreads();
    if (tid == 0) {
        int t = 0;
        for (int w = 0; w < 10; ++w) t += ired[w];
        s_ms = (float)t;
    }
    __syncthreads();

    float cs0 = 0.f, cs1 = 0.f, cs2 = 0.f, cs3 = 0.f;
    for (int mbq = 0; mbq < MQ/BM; mbq += 4) {
        cs0 += partial[(size_t)(mbq+0)*NTOT + tid];
        cs1 += partial[(size_t)(mbq+1)*NTOT + tid];
        cs2 += partial[(size_t)(mbq+2)*NTOT + tid];
        cs3 += partial[(size_t)(mbq+3)*NTOT + tid];
    }
    float cs = (cs0 + cs1) + (cs2 + cs3);
    float mar = cs / s_ms;
    float tv = mar * logf(mar + 1e-7f);
#pragma unroll
    for (int s = 32; s >= 1; s >>= 1) tv += __shfl_xor(tv, s, 64);
    if (lane == 0) fred[wid] = tv;
    __syncthreads();
    if (tid == 0) {
        float h0 = fred[0]+fred[1]+fred[2]+fred[3]+fred[4];
        float h1 = fred[5]+fred[6]+fred[7]+fred[8]+fred[9];
        out[QOUT] = expf(-h0) + expf(-h1);
    }
}

extern "C" void kernel_launch(void* const* d_in, const int* in_sizes, int n_in,
                              void* d_out, int out_size, void* d_ws, size_t ws_size,
                              hipStream_t stream) {
    const float* x    = (const float*)d_in[0];
    const float* W    = (const float*)d_in[1];
    const float* bias = (const float*)d_in[2];
    const float* cb   = (const float*)d_in[3];
    const float* gum  = (const float*)d_in[4];
    const int*   mask = (const int*)d_in[5];
    float* out = (float*)d_out;
    float* partial = (float*)d_ws;                 // [512][640] f32 = 1.31 MB
    unsigned short* Wt = (unsigned short*)((char*)d_ws + (size_t)MQ/BM*NTOT*4); // bf16 [640][512]

    wcvt<<<dim3(INQ/64, NTOT/64), 256, 0, stream>>>(W, Wt);
    qk1<<<dim3(MQ/BM, NBQ), THREADS, 0, stream>>>(x, Wt, bias, cb, gum, mask, out, partial);
    qk2<<<1, 640, 0, stream>>>(partial, mask, out);
}